// Round 9
// baseline (144.307 us; speedup 1.0000x reference)
//
#include <hip/hip_runtime.h>

#define HH 128
#define WW 128
#define CC 64
#define CO 64
#define BB 4
#define GG 8
#define CG 8
#define KK 9
#define HW (HH*WW)
#define PXT 16
#define NCH 18             // k''-chunks of 32: 576/32, no padding
#define NPOS (GG*KK*PXT)   // 1152 positions per block

typedef __attribute__((ext_vector_type(8))) short short8;
typedef __attribute__((ext_vector_type(4))) float floatx4;
typedef __attribute__((ext_vector_type(2))) float f32x2;

union S8I { short8 s; int i[4]; };
union FU { float f; unsigned u; };

__device__ inline short f2bf(float f) {
    FU v; v.f = f;
    return (short)((v.u + 0x7FFF + ((v.u >> 16) & 1)) >> 16);
}
__device__ inline unsigned rnd2(float f) {   // round-half-up bf16 in bits [31:16]
    FU v; v.f = f;
    return v.u + 0x8000u;
}
__device__ inline float bflo(int e) { union { int i; float f; } u; u.i = e << 16; return u.f; }
__device__ inline float bfhi(int e) { union { int i; float f; } u; u.i = e & 0xffff0000; return u.f; }

// ---- merged prep: blocks [0,144) pack weights; blocks [144,2192) transpose input ----
// k'' = (kk*8 + g)*8 + cg  (bit-cheap decode in the fused kernel)
__global__ __launch_bounds__(256)
void prep(const float* __restrict__ wt, const float* __restrict__ in,
          short* __restrict__ wf, short* __restrict__ in_t) {
    const int bid = blockIdx.x;
    if (bid < 144) {
        const int tid = bid * 256 + threadIdx.x;      // < 36864 = 576*64
        const int j  = tid & 7;
        const int L  = (tid >> 3) & 63;
        const int fid = tid >> 9;                     // 0..71
        const int ot = fid & 3;
        const int gc = fid >> 2;                      // 0..17
        const int kpp = gc * 32 + (L >> 4) * 8 + j;   // k'' in [0,576)
        const int o   = ot * 16 + (L & 15);
        const int cg  = kpp & 7;
        const int g   = (kpp >> 3) & 7;
        const int kk  = kpp >> 6;
        wf[tid] = f2bf(wt[o * 576 + (g * 8 + cg) * 9 + kk]);
    } else {
        const int idx = bid - 144;                    // 2048 blocks: 64 x 8 x 4
        const int bx = idx & 63;
        const int g  = (idx >> 6) & 7;
        const int b  = idx >> 9;
        const int p  = bx * 256 + threadIdx.x;
        const float* src = in + (b * CC + g * CG) * HW + p;
        short8 v;
        #pragma unroll
        for (int cg = 0; cg < CG; ++cg) v[cg] = f2bf(src[cg * HW]);
        *(short8*)(in_t + ((b * GG + g) * HW + p) * 8) = v;
    }
}

// Block: 256 thr / 4 waves, tile = (b, ho, 16 px). Grid (8,128,4)=4096.
// One barrier. Depth-2 SW pipeline on the corner gathers: A(i+1) issues 4
// scattered dwordx4 + weights while B(i) combines the previous position.
// State sized to ~75 VGPR (no scratch spill -> occupancy back to 4 blocks/CU).
__global__ __launch_bounds__(256, 4)
void dcn_fused(const short* __restrict__ in_t, const float* __restrict__ off,
               const float* __restrict__ msk, const short* __restrict__ wf,
               const float* __restrict__ bias, float* __restrict__ out)
{
    __shared__ short s_col[NCH * 512];   // [gc][lane][8] = 18432 B

    const int pxbase = blockIdx.x * PXT;
    const int ho = blockIdx.y;
    const int b  = blockIdx.z;
    const int t  = threadIdx.x;
    const int w = t >> 6, lane = t & 63;

    // ---- prefetch ALL offset/mask for this thread's positions (15 loads in flight) ----
    float pdy[5], pdx[5], pm[5];
    #pragma unroll
    for (int i = 0; i < 5; ++i) {
        const int pidx = t + i * 256;
        if (pidx < NPOS) {
            const int g  = (pidx >> 4) & 7;
            const int kk = pidx >> 7;
            const int base = ho * WW + pxbase + (pidx & 15);
            const int offc = (b * 144 + g * 18 + kk * 2) * HW + base;
            pdy[i] = off[offc];
            pdx[i] = off[offc + HW];
            pm[i]  = msk[(b * 72 + g * 9 + kk) * HW + base];
        }
    }

    // ---- acc init from bias (C/D: row o = w*16 + q4*4 + r, col px = n16) ----
    const int q4 = lane >> 4, n16 = lane & 15;
    floatx4 acc0, acc1;
    #pragma unroll
    for (int r = 0; r < 4; ++r) { acc0[r] = bias[w * 16 + q4 * 4 + r]; acc1[r] = 0.f; }

    const char* ib = (const char*)(in_t + (long)b * GG * HW * 8);

    // stage A: addresses + weights + issue 4 corner loads for slot i
    auto stageA = [&](int i, S8I* u, float* wv) {
        const int pidx = t + i * 256;
        if (pidx < NPOS) {
            const int g  = (pidx >> 4) & 7;
            const int kk = pidx >> 7;
            const int px = pxbase + (pidx & 15);
            const int ky = kk / 3, kx = kk - ky * 3;

            const float py  = (float)(ho - 1 + ky) + pdy[i];
            const float pxf = (float)(px - 1 + kx) + pdx[i];
            const float y0f = floorf(py), x0f = floorf(pxf);
            const float ly = py - y0f, lx = pxf - x0f;
            const int y0 = (int)y0f, x0 = (int)x0f;
            const int y1 = y0 + 1,  x1 = x0 + 1;

            const float vy0 = (y0 >= 0 && y0 < HH) ? 1.f : 0.f;
            const float vy1 = (y1 >= 0 && y1 < HH) ? 1.f : 0.f;
            const float vx0 = (x0 >= 0 && x0 < WW) ? 1.f : 0.f;
            const float vx1 = (x1 >= 0 && x1 < WW) ? 1.f : 0.f;
            const int y0c = min(max(y0, 0), HH - 1), y1c = min(max(y1, 0), HH - 1);
            const int x0c = min(max(x0, 0), WW - 1), x1c = min(max(x1, 0), WW - 1);

            const float m = pm[i];
            const float wy0 = (1.f - ly) * vy0 * m;
            const float wy1 = ly * vy1 * m;
            const float wx0 = (1.f - lx) * vx0;
            const float wx1 = lx * vx1;
            wv[0] = wy0 * wx0;  wv[1] = wy0 * wx1;
            wv[2] = wy1 * wx0;  wv[3] = wy1 * wx1;

            const int gsh = g << 18;
            const int y0sh = gsh + (y0c << 11), y1sh = gsh + (y1c << 11);
            const int x0sh = x0c << 4, x1sh = x1c << 4;
            u[0].s = *(const short8*)(ib + (y0sh + x0sh));
            u[1].s = *(const short8*)(ib + (y0sh + x1sh));
            u[2].s = *(const short8*)(ib + (y1sh + x0sh));
            u[3].s = *(const short8*)(ib + (y1sh + x1sh));
        }
    };

    // stage B: packed-f32 bilinear + bf16 pack + fragment write for slot i
    auto stageB = [&](int i, S8I* u, float* wv) {
        const int pidx = t + i * 256;
        if (pidx < NPOS) {
            const f32x2 W00 = {wv[0], wv[0]}, W01 = {wv[1], wv[1]};
            const f32x2 W10 = {wv[2], wv[2]}, W11 = {wv[3], wv[3]};
            S8I res;
            #pragma unroll
            for (int pc = 0; pc < 4; ++pc) {
                const int e00 = u[0].i[pc], e01 = u[1].i[pc];
                const int e10 = u[2].i[pc], e11 = u[3].i[pc];
                f32x2 a00 = {bflo(e00), bfhi(e00)};
                f32x2 a01 = {bflo(e01), bfhi(e01)};
                f32x2 a10 = {bflo(e10), bfhi(e10)};
                f32x2 a11 = {bflo(e11), bfhi(e11)};
                f32x2 v = a00 * W00;
                v += a01 * W01;
                v += a10 * W10;
                v += a11 * W11;
                res.i[pc] = (int)__builtin_amdgcn_perm(rnd2(v.y), rnd2(v.x), 0x07060302u);
            }
            *(short8*)(s_col + pidx * 8) = res.s;   // k'' row index IS pidx
        }
    };

    // ---- depth-2 pipeline over 5 position slots ----
    S8I ua[4], ub[4];
    float wa[4], wb[4];
    stageA(0, ua, wa);
    #pragma unroll
    for (int i = 0; i < 5; ++i) {
        if (i & 1) {
            if (i + 1 < 5) stageA(i + 1, ua, wa);
            stageB(i, ub, wb);
        } else {
            if (i + 1 < 5) stageA(i + 1, ub, wb);
            stageB(i, ua, wa);
        }
    }

    __syncthreads();   // the only barrier

    // ---- MFMA: 18 chunks, A-frags from L2-hot global, 2 acc chains ----
    #pragma unroll
    for (int gc = 0; gc < NCH; ++gc) {
        const short8 bfr = *(const short8*)&s_col[(gc * 64 + lane) * 8];
        const short8 afr = *(const short8*)&wf[((gc * 4 + w) * 64 + lane) * 8];
        if (gc & 1) acc1 = __builtin_amdgcn_mfma_f32_16x16x32_bf16(afr, bfr, acc1, 0, 0, 0);
        else        acc0 = __builtin_amdgcn_mfma_f32_16x16x32_bf16(afr, bfr, acc0, 0, 0, 0);
    }

    // ---- epilogue ----
    const int px = pxbase + n16;
    #pragma unroll
    for (int r = 0; r < 4; ++r) {
        const int o = w * 16 + q4 * 4 + r;
        out[((b * CO + o) * HH + ho) * WW + px] = acc0[r] + acc1[r];
    }
}

extern "C" void kernel_launch(void* const* d_in, const int* in_sizes, int n_in,
                              void* d_out, int out_size, void* d_ws, size_t ws_size,
                              hipStream_t stream) {
    const float* in   = (const float*)d_in[0];
    const float* off  = (const float*)d_in[1];
    const float* msk  = (const float*)d_in[2];
    const float* wt   = (const float*)d_in[3];
    const float* bias = (const float*)d_in[4];
    float* out = (float*)d_out;
    short* wf   = (short*)d_ws;            // 36864 shorts = 72 KB
    short* in_t = (short*)d_ws + 36864;    // 4*8*16384*8 shorts = 8 MB

    prep<<<144 + 2048, 256, 0, stream>>>(wt, in, wf, in_t);

    dim3 grid(WW / PXT, HH, BB);
    dcn_fused<<<grid, 256, 0, stream>>>(in_t, off, msk, wf, bias, out);
}

// Round 10
// 136.829 us; speedup vs baseline: 1.0547x; 1.0547x over previous
//
#include <hip/hip_runtime.h>

#define HH 128
#define WW 128
#define CC 64
#define CO 64
#define BB 4
#define GG 8
#define CG 8
#define KK 9
#define HW (HH*WW)
#define PXT 64

typedef __attribute__((ext_vector_type(8))) short short8;
typedef __attribute__((ext_vector_type(4))) float floatx4;
typedef __attribute__((ext_vector_type(2))) float f32x2;

union S8I { short8 s; int i[4]; };
union FU { float f; unsigned u; };

__device__ inline short f2bf(float f) {
    FU v; v.f = f;
    return (short)((v.u + 0x7FFF + ((v.u >> 16) & 1)) >> 16);
}
__device__ inline unsigned rnd2(float f) {   // round-half-up bf16 in bits [31:16]
    FU v; v.f = f;
    return v.u + 0x8000u;
}
__device__ inline float bflo(int e) { union { int i; float f; } u; u.i = e << 16; return u.f; }
__device__ inline float bfhi(int e) { union { int i; float f; } u; u.i = e & 0xffff0000; return u.f; }

// ---- merged prep ----
// A-frag layout for the half-K GEMM: fid = (h*9+gc)*4 + ot,
//   wf[fid*512 + L*8 + j] = bf16(W[o=ot*16+(L&15)][g=h*4+(L>>4)][cg=j][kk=gc])
// Input NCHW f32 -> in_t[b][g][y*W+x][cg] bf16 (16B per pixel-group).
__global__ __launch_bounds__(256)
void prep(const float* __restrict__ wt, const float* __restrict__ in,
          short* __restrict__ wf, short* __restrict__ in_t) {
    const int bid = blockIdx.x;
    if (bid < 144) {
        const int tid = bid * 256 + threadIdx.x;   // < 36864 = 576*64
        const int j   = tid & 7;
        const int L   = (tid >> 3) & 63;
        const int fid = tid >> 9;                  // (h*9+gc)*4 + ot, 0..71
        const int ot  = fid & 3;
        const int gch = fid >> 2;                  // h*9 + gc, 0..17
        const int h   = gch / 9, gc = gch - h * 9;
        const int o   = ot * 16 + (L & 15);
        const int g   = h * 4 + (L >> 4);
        wf[tid] = f2bf(wt[o * 576 + (g * 8 + j) * 9 + gc]);
    } else {
        const int idx = bid - 144;                 // 2048 blocks: 64 x 8 x 4
        const int bx = idx & 63;
        const int g  = (idx >> 6) & 7;
        const int b  = idx >> 9;
        const int p  = bx * 256 + threadIdx.x;
        const float* src = in + (b * CC + g * CG) * HW + p;
        short8 v;
        #pragma unroll
        for (int cg = 0; cg < CG; ++cg) v[cg] = f2bf(src[cg * HW]);
        *(short8*)(in_t + ((b * GG + g) * HW + p) * 8) = v;
    }
}

// Block: 256 thr / 4 waves, tile = (b, ho, 64 px) -> 64o x 64px. Grid (2,128,4)=1024.
// Gather locality: wave w handles group g=h*4+w, tap kk=i (unroll const), lanes =
// 64 CONSECUTIVE px of one group -> corner wave-loads hit ~2x fewer distinct
// 64B lines than the round-5..9 (16px x 4 groups) layout. K in 2 halves so
// s_col = 9 chunks x 4 strips = 36.9 KB -> 4 blocks/CU.
__global__ __launch_bounds__(256, 4)
void dcn_fused(const short* __restrict__ in_t, const float* __restrict__ off,
               const float* __restrict__ msk, const short* __restrict__ wf,
               const float* __restrict__ bias, float* __restrict__ out)
{
    __shared__ short s_col[9 * 4 * 512];   // [gc][strip][lane][8] = 36864 B

    const int pxbase = blockIdx.x * PXT;
    const int ho = blockIdx.y;
    const int b  = blockIdx.z;
    const int t  = threadIdx.x;
    const int w = t >> 6, lane = t & 63;
    const int px = pxbase + lane;
    const int q4 = lane >> 4, n16 = lane & 15;
    const int basepix = ho * WW + px;

    floatx4 acc[4];
    #pragma unroll
    for (int ot = 0; ot < 4; ++ot)
        #pragma unroll
        for (int r = 0; r < 4; ++r)
            acc[ot][r] = bias[ot * 16 + q4 * 4 + r];

    const char* ib = (const char*)(in_t + (long)b * GG * HW * 8);

    #pragma unroll
    for (int h = 0; h < 2; ++h) {
        const int g = h * 4 + w;     // this wave's offset group for the gather

        // ---- preload off/mask: 27 independent fully-coalesced loads ----
        float pdy[9], pdx[9], pm[9];
        #pragma unroll
        for (int i = 0; i < 9; ++i) {
            const int offc = (b * 144 + g * 18 + i * 2) * HW + basepix;
            pdy[i] = off[offc];
            pdx[i] = off[offc + HW];
            pm[i]  = msk[(b * 72 + g * 9 + i) * HW + basepix];
        }

        if (h) __syncthreads();      // previous half's GEMM done before overwrite

        // ---- gather: 9 taps, lanes = 64 consecutive px of group g ----
        const int gsh = g << 18;
        #pragma unroll
        for (int i = 0; i < 9; ++i) {
            const int ky = i / 3, kx = i - (i / 3) * 3;   // compile-time consts

            const float py  = (float)(ho - 1 + ky) + pdy[i];
            const float pxf = (float)(px - 1 + kx) + pdx[i];
            const float y0f = floorf(py), x0f = floorf(pxf);
            const float ly = py - y0f, lx = pxf - x0f;
            const int y0 = (int)y0f, x0 = (int)x0f;
            const int y1 = y0 + 1,  x1 = x0 + 1;

            const float vy0 = (y0 >= 0 && y0 < HH) ? 1.f : 0.f;
            const float vy1 = (y1 >= 0 && y1 < HH) ? 1.f : 0.f;
            const float vx0 = (x0 >= 0 && x0 < WW) ? 1.f : 0.f;
            const float vx1 = (x1 >= 0 && x1 < WW) ? 1.f : 0.f;
            const int y0c = min(max(y0, 0), HH - 1), y1c = min(max(y1, 0), HH - 1);
            const int x0c = min(max(x0, 0), WW - 1), x1c = min(max(x1, 0), WW - 1);

            const float m = pm[i];
            const float wy0 = (1.f - ly) * vy0 * m;
            const float wy1 = ly * vy1 * m;
            const float wx0 = (1.f - lx) * vx0;
            const float wx1 = lx * vx1;
            const float w00 = wy0 * wx0, w01 = wy0 * wx1;
            const float w10 = wy1 * wx0, w11 = wy1 * wx1;

            const int y0sh = gsh + (y0c << 11), y1sh = gsh + (y1c << 11);
            const int x0sh = x0c << 4, x1sh = x1c << 4;
            S8I u00, u01, u10, u11;
            u00.s = *(const short8*)(ib + (y0sh + x0sh));
            u01.s = *(const short8*)(ib + (y0sh + x1sh));
            u10.s = *(const short8*)(ib + (y1sh + x0sh));
            u11.s = *(const short8*)(ib + (y1sh + x1sh));

            const f32x2 W00 = {w00, w00}, W01 = {w01, w01};
            const f32x2 W10 = {w10, w10}, W11 = {w11, w11};
            S8I res;
            #pragma unroll
            for (int pc = 0; pc < 4; ++pc) {
                const int e00 = u00.i[pc], e01 = u01.i[pc];
                const int e10 = u10.i[pc], e11 = u11.i[pc];
                f32x2 a00 = {bflo(e00), bfhi(e00)};
                f32x2 a01 = {bflo(e01), bfhi(e01)};
                f32x2 a10 = {bflo(e10), bfhi(e10)};
                f32x2 a11 = {bflo(e11), bfhi(e11)};
                f32x2 v = a00 * W00;
                v += a01 * W01;
                v += a10 * W10;
                v += a11 * W11;
                res.i[pc] = (int)__builtin_amdgcn_perm(rnd2(v.y), rnd2(v.x), 0x07060302u);
            }

            // chunk gc=i, within-chunk k = w*8+cg, strip p=q4, col n16
            *(short8*)(s_col + ((i * 4 + q4) * 64 + w * 16 + n16) * 8) = res.s;
        }

        __syncthreads();

        // ---- GEMM: 9 chunks; wave w = px strip w; A-frags from L2-hot global ----
        #pragma unroll
        for (int gc = 0; gc < 9; ++gc) {
            const short8 bfr = *(const short8*)&s_col[((gc * 4 + w) * 64 + lane) * 8];
            #pragma unroll
            for (int ot = 0; ot < 4; ++ot) {
                const short8 afr = *(const short8*)&wf[((h * 9 + gc) * 4 + ot) * 512 + lane * 8];
                acc[ot] = __builtin_amdgcn_mfma_f32_16x16x32_bf16(afr, bfr, acc[ot], 0, 0, 0);
            }
        }
    }

    // ---- epilogue: o = ot*16 + q4*4 + r, px = pxbase + w*16 + n16 ----
    const int pxo = pxbase + w * 16 + n16;
    #pragma unroll
    for (int ot = 0; ot < 4; ++ot)
        #pragma unroll
        for (int r = 0; r < 4; ++r)
            out[((b * CO + ot * 16 + q4 * 4 + r) * HH + ho) * WW + pxo] = acc[ot][r];
}

extern "C" void kernel_launch(void* const* d_in, const int* in_sizes, int n_in,
                              void* d_out, int out_size, void* d_ws, size_t ws_size,
                              hipStream_t stream) {
    const float* in   = (const float*)d_in[0];
    const float* off  = (const float*)d_in[1];
    const float* msk  = (const float*)d_in[2];
    const float* wt   = (const float*)d_in[3];
    const float* bias = (const float*)d_in[4];
    float* out = (float*)d_out;
    short* wf   = (short*)d_ws;            // 36864 shorts = 72 KB
    short* in_t = (short*)d_ws + 36864;    // 4*8*16384*8 shorts = 8 MB

    prep<<<144 + 2048, 256, 0, stream>>>(wt, in, wf, in_t);

    dim3 grid(WW / PXT, HH, BB);
    dcn_fused<<<grid, 256, 0, stream>>>(in_t, off, msk, wf, bias, out);
}